// Round 18
// baseline (267.358 us; speedup 1.0000x reference)
//
#include <hip/hip_runtime.h>
#include <hip/hip_bf16.h>
#include <hip/hip_fp16.h>

// Problem constants
#define N_NODES 50000
#define N_EDGES 500000
#define IN_CH   128
#define D       256   // HEADS * OUT_CH
#define UDIM    512   // HEADS * 128 (u and y width)
#define OUT_CH  64
#define HEADS   4
#define NC      49    // scan chunks of 1024: ceil(50000/1024)
#define PCAP    1024  // LDS payload staging capacity per block

// K1 grid sections
#define NB_X16  6250  // 50000*128/4/256
#define NB_HIST 1954  // ceil(500000/256)
#define NB_MB   256   // 512 M-rows, 2 per block
#define NB_ZB   128   // 512 Zc-rows, 4 per block
// K4 grid sections (gemm_u || scatter)
#define NB_GEMM 1564  // 391 * 4
#define NB_SCAT 1954  // ceil(500000/256)

typedef _Float16 half8 __attribute__((ext_vector_type(8)));   // 4 VGPRs (MFMA A/B)
typedef _Float16 half2_t __attribute__((ext_vector_type(2))); // 1 VGPR packed
typedef float   floatx4 __attribute__((ext_vector_type(4)));  // 4 VGPRs (MFMA C/D)

// ---------------------------------------------------------------------------
// K1 (fused): x16 convert | tgt histogram | M16t build | Zc16t build
// ---------------------------------------------------------------------------
__global__ __launch_bounds__(256) void k1_prep_kernel(const float* __restrict__ x,
                                                      __half* __restrict__ x16,
                                                      const int* __restrict__ ei,
                                                      int* __restrict__ cnt,
                                                      double* __restrict__ S,
                                                      const float* __restrict__ Wq,
                                                      const float* __restrict__ Wk,
                                                      const float* __restrict__ Wv,
                                                      const float* __restrict__ Wout,
                                                      __half* __restrict__ M16t,
                                                      __half* __restrict__ Zc16t) {
    __shared__ float sbuf[4][64];
    const int b = blockIdx.x, tid = threadIdx.x;
    if (b < NB_X16) {
        int i = b * 256 + tid;
        if (i < HEADS) S[i] = 0.0;
        int k = i * 4;
        if (k < N_NODES * IN_CH) {
            float4 v = *(const float4*)(x + k);
            union { __half2 h[2]; uint2 u; } pk;
            pk.h[0] = __floats2half2_rn(v.x, v.y);
            pk.h[1] = __floats2half2_rn(v.z, v.w);
            *(uint2*)(x16 + k) = pk.u;
        }
    } else if (b < NB_X16 + NB_HIST) {
        int e = (b - NB_X16) * 256 + tid;
        if (e < N_EDGES) atomicAdd(&cnt[ei[N_EDGES + e]], 1);
    } else if (b < NB_X16 + NB_HIST + NB_MB) {
        const int r = (b - NB_X16 - NB_HIST) * 2 + (tid >> 7);  // M-row 0..511
        const int i = tid & 127;
        const int h = r >> 7, j = r & 127;
        float* buf = sbuf[tid >> 7];
        if (i < 64) buf[i] = Wk[(size_t)j * D + h * 64 + i];
        __syncthreads();
        const float4* qr = (const float4*)(Wq + (size_t)i * D + h * 64);
        float s = 0.f;
        #pragma unroll
        for (int c4 = 0; c4 < 16; ++c4) {
            float4 q = qr[c4];
            s += q.x * buf[c4 * 4] + q.y * buf[c4 * 4 + 1]
               + q.z * buf[c4 * 4 + 2] + q.w * buf[c4 * 4 + 3];
        }
        M16t[(size_t)r * IN_CH + i] = __float2half(s);
    } else {
        const int r = (b - NB_X16 - NB_HIST - NB_MB) * 4 + (tid >> 6); // Zc-row
        const int c = tid & 63;
        const int h = r >> 7, i = r & 127;
        float* buf = sbuf[tid >> 6];
        buf[c] = Wv[(size_t)i * D + h * 64 + c];
        __syncthreads();
        float s = 0.f;
        #pragma unroll 8
        for (int j = 0; j < 64; ++j)
            s += buf[j] * Wout[(size_t)(h * 64 + j) * OUT_CH + c];
        Zc16t[(size_t)c * UDIM + r] = __float2half(s);
    }
}

// ---------------------------------------------------------------------------
// K2: scan_reduce — per-1024-chunk sums of cnt into csum (49 blocks)
// ---------------------------------------------------------------------------
__global__ __launch_bounds__(256) void k2_scan_reduce_kernel(const int* __restrict__ cnt,
                                                             int* __restrict__ csum) {
    const int b = blockIdx.x, tid = threadIdx.x;
    const int lane = tid & 63, wid = tid >> 6;
    int s = 0;
    int idx0 = b * 1024 + tid * 4;
    #pragma unroll
    for (int i = 0; i < 4; ++i) {
        int idx = idx0 + i;
        if (idx < N_NODES) s += cnt[idx];
    }
    #pragma unroll
    for (int m = 1; m < 64; m <<= 1) s += __shfl_xor(s, m, 64);
    __shared__ int w4[4];
    if (lane == 0) w4[wid] = s;
    __syncthreads();
    if (tid == 0) csum[b] = w4[0] + w4[1] + w4[2] + w4[3];
}

// ---------------------------------------------------------------------------
// K3: scan_chunks with inlined 49-element top-scan
// ---------------------------------------------------------------------------
__global__ __launch_bounds__(256) void k3_scan_chunks_kernel(int* __restrict__ cnt,
                                                             const int* __restrict__ csum,
                                                             int* __restrict__ rp) {
    __shared__ int stop[64];
    __shared__ int wsum[4];
    const int b = blockIdx.x, tid = threadIdx.x;
    const int lane = tid & 63, wid = tid >> 6;
    if (tid < 64) stop[tid] = (tid < NC) ? csum[tid] : 0;
    __syncthreads();
    int base = 0;
    for (int w = 0; w < b; ++w) base += stop[w];
    int v[4];
    const int idx0 = b * 1024 + tid * 4;
    #pragma unroll
    for (int i = 0; i < 4; ++i) {
        int idx = idx0 + i;
        v[i] = (idx < N_NODES) ? cnt[idx] : 0;
    }
    int tsum = v[0] + v[1] + v[2] + v[3];
    int x = tsum;
    #pragma unroll
    for (int d = 1; d < 64; d <<= 1) {
        int y = __shfl_up(x, d, 64);
        if (lane >= d) x += y;
    }
    if (lane == 63) wsum[wid] = x;
    __syncthreads();
    int woff = 0;
    for (int w = 0; w < wid; ++w) woff += wsum[w];
    int excl = base + woff + x - tsum;
    #pragma unroll
    for (int i = 0; i < 4; ++i) {
        int idx = idx0 + i;
        if (idx < N_NODES) { rp[idx] = excl; cnt[idx] = excl; }
        excl += v[i];
    }
}

// ---------------------------------------------------------------------------
// K4 (fused): GEMM1 (BK=64 two-pass; LDS 36.9 KB -> 4 blocks/CU) || scatter.
//   [0, NB_GEMM)        : u16 = x16 @ M16t^T, 128x128 tile, acc across 2 kt
//   [NB_GEMM, +NB_SCAT) : scatter edges -> payload {src, w}
// ---------------------------------------------------------------------------
__global__ __launch_bounds__(256) void k4_gemmu_scatter_kernel(const __half* __restrict__ x16,
                                                               const __half* __restrict__ M16t,
                                                               __half* __restrict__ u16,
                                                               const int* __restrict__ ei,
                                                               const float* __restrict__ ew,
                                                               int* __restrict__ cnt,
                                                               int2* __restrict__ payload) {
    __shared__ __half Ax[128][72];
    __shared__ __half Bm[128][72];
    const int tid = threadIdx.x;
    if (blockIdx.x >= NB_GEMM) {
        int e = (blockIdx.x - NB_GEMM) * 256 + tid;
        if (e < N_EDGES) {
            int s = ei[e], t = ei[N_EDGES + e];
            int pos = atomicAdd(&cnt[t], 1);
            payload[pos] = make_int2(s, __float_as_int(ew[e]));
        }
        return;
    }
    const int m0 = (blockIdx.x % 391) * 128;
    const int colbase = (blockIdx.x / 391) * 128;
    const int w = tid >> 6, lane = tid & 63;
    const int mrow = lane & 15, quad = lane >> 4;

    floatx4 acc[2][8];
    #pragma unroll
    for (int mt = 0; mt < 2; ++mt)
        #pragma unroll
        for (int nt = 0; nt < 8; ++nt)
            acc[mt][nt] = (floatx4){0.f, 0.f, 0.f, 0.f};

    for (int kt = 0; kt < 2; ++kt) {
        const int k0 = kt * 64;
        {   // stage 128x64-half tiles: r = tid>>1, part = tid&1 (32 halves = 4 uint4)
            const int r = tid >> 1, part = tid & 1;
            uint4 va[4];
            if (m0 + r < N_NODES) {
                const uint4* src = (const uint4*)(x16 + (size_t)(m0 + r) * IN_CH + k0 + part * 32);
                #pragma unroll
                for (int q = 0; q < 4; ++q) va[q] = src[q];
            } else {
                #pragma unroll
                for (int q = 0; q < 4; ++q) va[q] = make_uint4(0u, 0u, 0u, 0u);
            }
            uint4* da = (uint4*)&Ax[r][part * 32];
            #pragma unroll
            for (int q = 0; q < 4; ++q) da[q] = va[q];
            const uint4* sb = (const uint4*)(M16t + (size_t)(colbase + r) * IN_CH + k0 + part * 32);
            uint4* db = (uint4*)&Bm[r][part * 32];
            #pragma unroll
            for (int q = 0; q < 4; ++q) db[q] = sb[q];
        }
        __syncthreads();
        half8 a[2][2];
        #pragma unroll
        for (int mt = 0; mt < 2; ++mt)
            #pragma unroll
            for (int ks = 0; ks < 2; ++ks)
                a[mt][ks] = *(const half8*)&Ax[w * 32 + mt * 16 + mrow][ks * 32 + quad * 8];
        #pragma unroll
        for (int nt = 0; nt < 8; ++nt) {
            #pragma unroll
            for (int ks = 0; ks < 2; ++ks) {
                half8 bfr = *(const half8*)&Bm[nt * 16 + mrow][ks * 32 + quad * 8];
                acc[0][nt] = __builtin_amdgcn_mfma_f32_16x16x32_f16(a[0][ks], bfr, acc[0][nt], 0, 0, 0);
                acc[1][nt] = __builtin_amdgcn_mfma_f32_16x16x32_f16(a[1][ks], bfr, acc[1][nt], 0, 0, 0);
            }
        }
        __syncthreads();
    }
    // epilogue: transpose C through Ax in two 64-column halves
    #pragma unroll
    for (int half = 0; half < 2; ++half) {
        #pragma unroll
        for (int mt = 0; mt < 2; ++mt)
            #pragma unroll
            for (int nt = 0; nt < 4; ++nt)
                #pragma unroll
                for (int r = 0; r < 4; ++r)
                    Ax[w * 32 + mt * 16 + quad * 4 + r][nt * 16 + mrow] =
                        __float2half(acc[mt][half * 4 + nt][r]);
        __syncthreads();
        {
            const int r = tid >> 1, part = tid & 1;
            if (m0 + r < N_NODES) {
                const uint4* s4 = (const uint4*)&Ax[r][part * 32];
                uint4* d4 = (uint4*)(u16 + (size_t)(m0 + r) * UDIM + colbase + half * 64 + part * 32);
                #pragma unroll
                for (int q = 0; q < 4; ++q) d4[q] = s4[q];
            }
        }
        __syncthreads();
    }
}

// ---------------------------------------------------------------------------
// Fused edge kernel v5 (round-15 best): LDS payload staging + head-striped
// lanes. Block = 16 consecutive tgt nodes -> ONE contiguous payload span.
// ---------------------------------------------------------------------------
__global__ __launch_bounds__(256) void edge_fused_kernel(const __half* __restrict__ u16,
                                                         const __half* __restrict__ x16,
                                                         const int* __restrict__ rp,
                                                         const int* __restrict__ cnt,
                                                         const int2* __restrict__ payload,
                                                         const float* __restrict__ We,
                                                         __half* __restrict__ y16,
                                                         double* __restrict__ S) {
    __shared__ int2 pbuf[PCAP];
    __shared__ float sblk[4];
    const int tid = threadIdx.x;
    const int nodebase = blockIdx.x * 16;

    const int span0 = rp[nodebase];
    const int span1 = cnt[nodebase + 15];
    const int span_len = min(span1 - span0, PCAP);
    for (int i = tid; i < span_len; i += 256) pbuf[i] = payload[span0 + i];
    if (tid < 4) sblk[tid] = 0.f;
    __syncthreads();

    const int l16 = tid & 15;
    const int h = l16 >> 2;          // head 0..3
    const int q = l16 & 3;           // channel quarter 0..3
    const int node = nodebase + (tid >> 4);
    const float wev = We[h];

    uint4 ur4[4];
    {
        const uint4* ub = (const uint4*)(u16 + (size_t)node * UDIM + h * 128 + q * 32);
        ur4[0] = ub[0]; ur4[1] = ub[1]; ur4[2] = ub[2]; ur4[3] = ub[3];
    }
    const half2_t* uh = (const half2_t*)ur4;    // 16 half2

    half2_t yacc[16];
    #pragma unroll
    for (int t = 0; t < 16; ++t) yacc[t] = (half2_t){(_Float16)0.f, (_Float16)0.f};

    float sacc = 0.f;
    const int start = rp[node];
    const int end = cnt[node];

    auto getpl = [&](int e) -> int2 {
        int idx = e - span0;
        return (idx < PCAP) ? pbuf[idx] : payload[e];
    };

    int2 pl = make_int2(0, 0);
    uint4 xr[4];
    if (start < end) {
        pl = getpl(start);
        const uint4* xb = (const uint4*)(x16 + (size_t)pl.x * IN_CH + q * 32);
        xr[0] = xb[0]; xr[1] = xb[1]; xr[2] = xb[2]; xr[3] = xb[3];
    }
    for (int e = start; e < end; ++e) {
        int2 pln = pl;
        uint4 xrn[4] = {xr[0], xr[1], xr[2], xr[3]};
        if (e + 1 < end) {
            pln = getpl(e + 1);
            const uint4* xb = (const uint4*)(x16 + (size_t)pln.x * IN_CH + q * 32);
            xrn[0] = xb[0]; xrn[1] = xb[1]; xrn[2] = xb[2]; xrn[3] = xb[3];
        }
        const half2_t* xh = (const half2_t*)xr;
        float dot = 0.f;
        #pragma unroll
        for (int t = 0; t < 16; ++t)
            dot = __builtin_amdgcn_fdot2(uh[t], xh[t], dot, false);
        dot += __shfl_xor(dot, 1, 16);
        dot += __shfl_xor(dot, 2, 16);
        float l = dot * 0.125f + __int_as_float(pl.y) * wev;
        l = fmaxf(l, 0.2f * l);          // leaky_relu(0.2)
        float p = __expf(l);
        if (q == 0) sacc += p;
        half2_t p2 = (half2_t){(_Float16)p, (_Float16)p};
        #pragma unroll
        for (int t = 0; t < 16; ++t)
            yacc[t] = p2 * xh[t] + yacc[t];   // v_pk_fma_f16
        pl = pln;
        xr[0] = xrn[0]; xr[1] = xrn[1]; xr[2] = xrn[2]; xr[3] = xrn[3];
    }
    {
        uint4* yo = (uint4*)(y16 + (size_t)node * UDIM + h * 128 + q * 32);
        const uint4* ys = (const uint4*)yacc;
        yo[0] = ys[0]; yo[1] = ys[1]; yo[2] = ys[2]; yo[3] = ys[3];
    }
    __syncthreads();
    if (q == 0) atomicAdd(&sblk[h], sacc);
    __syncthreads();
    if (tid < 4) atomicAdd(&S[tid], (double)sblk[tid]);
}

// ---------------------------------------------------------------------------
// GEMM2 (MFMA): out = sum_h invs[h] * (y16_h @ Zc16t_h^T) + b_out.
// 64-row M-tiles (782 blocks, LDS 34.8 KB -> 4 blocks/CU); one m-tile/wave.
// Staging: A 64x128 halves = 16 KB -> 4 uint4/thread; B same.
// ---------------------------------------------------------------------------
__global__ __launch_bounds__(256) void gemm_out_mfma_kernel(const __half* __restrict__ y16,
                                                            const __half* __restrict__ Zc16t,
                                                            const double* __restrict__ S,
                                                            const float* __restrict__ b_out,
                                                            float* __restrict__ out) {
    __shared__ __half Ay[64][136];
    __shared__ __half Bz[64][136];
    __shared__ float invs_s[4];
    const int m0 = blockIdx.x * 64;
    const int tid = threadIdx.x;
    if (tid < 4) invs_s[tid] = (float)(1.0 / S[tid]);

    const int w = tid >> 6, lane = tid & 63;
    const int mrow = lane & 15, quad = lane >> 4;

    floatx4 result[4];
    #pragma unroll
    for (int nt = 0; nt < 4; ++nt)
        result[nt] = (floatx4){0.f, 0.f, 0.f, 0.f};

    for (int h = 0; h < HEADS; ++h) {
        {   // stage A: y16 rows [m0,m0+64), cols [h*128,+128): 4 uint4/thread
            const int r = tid >> 2, part = tid & 3;
            uint4 va[4];
            if (m0 + r < N_NODES) {
                const uint4* src = (const uint4*)(y16 + (size_t)(m0 + r) * UDIM + h * 128 + part * 32);
                #pragma unroll
                for (int qq = 0; qq < 4; ++qq) va[qq] = src[qq];
            } else {
                #pragma unroll
                for (int qq = 0; qq < 4; ++qq) va[qq] = make_uint4(0u, 0u, 0u, 0u);
            }
            uint4* da = (uint4*)&Ay[r][part * 32];
            #pragma unroll
            for (int qq = 0; qq < 4; ++qq) da[qq] = va[qq];
        }
        {   // stage B: Zc16t rows [0,64), cols [h*128,+128): 4 uint4/thread
            const int r = tid >> 2, part = tid & 3;
            const uint4* sb = (const uint4*)(Zc16t + (size_t)r * UDIM + h * 128 + part * 32);
            uint4* db = (uint4*)&Bz[r][part * 32];
            #pragma unroll
            for (int qq = 0; qq < 4; ++qq) db[qq] = sb[qq];
        }
        __syncthreads();

        half8 a[4];
        #pragma unroll
        for (int ks = 0; ks < 4; ++ks)
            a[ks] = *(const half8*)&Ay[w * 16 + mrow][ks * 32 + quad * 8];

        floatx4 acc[4];
        #pragma unroll
        for (int nt = 0; nt < 4; ++nt)
            acc[nt] = (floatx4){0.f, 0.f, 0.f, 0.f};

        #pragma unroll
        for (int nt = 0; nt < 4; ++nt) {
            #pragma unroll
            for (int ks = 0; ks < 4; ++ks) {
                half8 bfr = *(const half8*)&Bz[nt * 16 + mrow][ks * 32 + quad * 8];
                acc[nt] = __builtin_amdgcn_mfma_f32_16x16x32_f16(a[ks], bfr, acc[nt], 0, 0, 0);
            }
        }
        const float inv = invs_s[h];
        #pragma unroll
        for (int nt = 0; nt < 4; ++nt) {
            result[nt][0] += inv * acc[nt][0];
            result[nt][1] += inv * acc[nt][1];
            result[nt][2] += inv * acc[nt][2];
            result[nt][3] += inv * acc[nt][3];
        }
        __syncthreads();
    }
    float bcol[4];
    #pragma unroll
    for (int nt = 0; nt < 4; ++nt) bcol[nt] = b_out[nt * 16 + mrow];
    #pragma unroll
    for (int r = 0; r < 4; ++r) {
        int row = m0 + w * 16 + quad * 4 + r;
        if (row < N_NODES) {
            float* dst = out + (size_t)row * OUT_CH;
            #pragma unroll
            for (int nt = 0; nt < 4; ++nt)
                dst[nt * 16 + mrow] = result[nt][r] + bcol[nt];
        }
    }
}

// ---------------------------------------------------------------------------
// Launch
// ---------------------------------------------------------------------------
extern "C" void kernel_launch(void* const* d_in, const int* in_sizes, int n_in,
                              void* d_out, int out_size, void* d_ws, size_t ws_size,
                              hipStream_t stream) {
    const float* x     = (const float*)d_in[0];
    const int*   ei    = (const int*)d_in[1];   // [2, E] int32
    const float* ew    = (const float*)d_in[2];
    const float* Wq    = (const float*)d_in[3];
    const float* Wk    = (const float*)d_in[4];
    const float* Wv    = (const float*)d_in[5];
    const float* We    = (const float*)d_in[6];
    const float* Wout  = (const float*)d_in[7];
    const float* b_out = (const float*)d_in[8];
    float* out = (float*)d_out;

    // workspace layout (~120 MB)
    __half* u16   = (__half*)d_ws;                          // 50000*512*2 = 51.2 MB
    __half* y16   = u16 + (size_t)N_NODES * UDIM;           // 51.2 MB
    __half* x16   = y16 + (size_t)N_NODES * UDIM;           // 12.8 MB
    double* S     = (double*)(x16 + (size_t)N_NODES * IN_CH);  // 4 doubles
    __half* M16t  = (__half*)(S + HEADS);                   // 512*128*2 = 128 KB
    __half* Zc16t = M16t + UDIM * IN_CH;                    // 64*512*2 = 64 KB
    int*    rp    = (int*)(Zc16t + OUT_CH * UDIM);          // 50000
    int*    cnt   = rp + N_NODES;                           // 50000
    int*    csum  = cnt + N_NODES;                          // 64
    int2*   payload = (int2*)(csum + 64);                   // 500000*8 = 4 MB

    hipMemsetAsync(cnt, 0, N_NODES * sizeof(int), stream);
    k1_prep_kernel<<<NB_X16 + NB_HIST + NB_MB + NB_ZB, 256, 0, stream>>>(
        x, x16, ei, cnt, S, Wq, Wk, Wv, Wout, M16t, Zc16t);
    k2_scan_reduce_kernel<<<NC, 256, 0, stream>>>(cnt, csum);
    k3_scan_chunks_kernel<<<NC, 256, 0, stream>>>(cnt, csum, rp);
    k4_gemmu_scatter_kernel<<<NB_GEMM + NB_SCAT, 256, 0, stream>>>(
        x16, M16t, u16, ei, ew, cnt, payload);
    edge_fused_kernel<<<N_NODES / 16, 256, 0, stream>>>(u16, x16, rp, cnt, payload, We, y16, S);
    gemm_out_mfma_kernel<<<(N_NODES + 63) / 64, 256, 0, stream>>>(y16, Zc16t, S, b_out, out);
}

// Round 19
// 262.921 us; speedup vs baseline: 1.0169x; 1.0169x over previous
//
#include <hip/hip_runtime.h>
#include <hip/hip_bf16.h>
#include <hip/hip_fp16.h>

// Problem constants
#define N_NODES 50000
#define N_EDGES 500000
#define IN_CH   128
#define D       256   // HEADS * OUT_CH
#define UDIM    512   // HEADS * 128 (u and y width)
#define OUT_CH  64
#define HEADS   4
#define NC      49    // scan chunks of 1024: ceil(50000/1024)
#define PCAP    1024  // LDS payload staging capacity per block

// K1 grid sections
#define NB_X16  6250  // 50000*128/4/256
#define NB_HIST 1954  // ceil(500000/256)
#define NB_MB   256   // 512 M-rows, 2 per block
#define NB_ZB   128   // 512 Zc-rows, 4 per block
// K4 grid sections (gemm_u || scatter)
#define NB_GEMM 1564  // 391 * 4
#define NB_SCAT 1954  // ceil(500000/256)

typedef _Float16 half8 __attribute__((ext_vector_type(8)));   // 4 VGPRs (MFMA A/B)
typedef _Float16 half2_t __attribute__((ext_vector_type(2))); // 1 VGPR packed
typedef float   floatx4 __attribute__((ext_vector_type(4)));  // 4 VGPRs (MFMA C/D)

// ---------------------------------------------------------------------------
// K1 (fused): x16 convert | tgt histogram | M16t build | Zc16t build
// ---------------------------------------------------------------------------
__global__ __launch_bounds__(256) void k1_prep_kernel(const float* __restrict__ x,
                                                      __half* __restrict__ x16,
                                                      const int* __restrict__ ei,
                                                      int* __restrict__ cnt,
                                                      double* __restrict__ S,
                                                      const float* __restrict__ Wq,
                                                      const float* __restrict__ Wk,
                                                      const float* __restrict__ Wv,
                                                      const float* __restrict__ Wout,
                                                      __half* __restrict__ M16t,
                                                      __half* __restrict__ Zc16t) {
    __shared__ float sbuf[4][64];
    const int b = blockIdx.x, tid = threadIdx.x;
    if (b < NB_X16) {
        int i = b * 256 + tid;
        if (i < HEADS) S[i] = 0.0;
        int k = i * 4;
        if (k < N_NODES * IN_CH) {
            float4 v = *(const float4*)(x + k);
            union { __half2 h[2]; uint2 u; } pk;
            pk.h[0] = __floats2half2_rn(v.x, v.y);
            pk.h[1] = __floats2half2_rn(v.z, v.w);
            *(uint2*)(x16 + k) = pk.u;
        }
    } else if (b < NB_X16 + NB_HIST) {
        int e = (b - NB_X16) * 256 + tid;
        if (e < N_EDGES) atomicAdd(&cnt[ei[N_EDGES + e]], 1);
    } else if (b < NB_X16 + NB_HIST + NB_MB) {
        const int r = (b - NB_X16 - NB_HIST) * 2 + (tid >> 7);  // M-row 0..511
        const int i = tid & 127;
        const int h = r >> 7, j = r & 127;
        float* buf = sbuf[tid >> 7];
        if (i < 64) buf[i] = Wk[(size_t)j * D + h * 64 + i];
        __syncthreads();
        const float4* qr = (const float4*)(Wq + (size_t)i * D + h * 64);
        float s = 0.f;
        #pragma unroll
        for (int c4 = 0; c4 < 16; ++c4) {
            float4 q = qr[c4];
            s += q.x * buf[c4 * 4] + q.y * buf[c4 * 4 + 1]
               + q.z * buf[c4 * 4 + 2] + q.w * buf[c4 * 4 + 3];
        }
        M16t[(size_t)r * IN_CH + i] = __float2half(s);
    } else {
        const int r = (b - NB_X16 - NB_HIST - NB_MB) * 4 + (tid >> 6); // Zc-row
        const int c = tid & 63;
        const int h = r >> 7, i = r & 127;
        float* buf = sbuf[tid >> 6];
        buf[c] = Wv[(size_t)i * D + h * 64 + c];
        __syncthreads();
        float s = 0.f;
        #pragma unroll 8
        for (int j = 0; j < 64; ++j)
            s += buf[j] * Wout[(size_t)(h * 64 + j) * OUT_CH + c];
        Zc16t[(size_t)c * UDIM + r] = __float2half(s);
    }
}

// ---------------------------------------------------------------------------
// K2: scan_reduce — per-1024-chunk sums of cnt into csum (49 blocks)
// ---------------------------------------------------------------------------
__global__ __launch_bounds__(256) void k2_scan_reduce_kernel(const int* __restrict__ cnt,
                                                             int* __restrict__ csum) {
    const int b = blockIdx.x, tid = threadIdx.x;
    const int lane = tid & 63, wid = tid >> 6;
    int s = 0;
    int idx0 = b * 1024 + tid * 4;
    #pragma unroll
    for (int i = 0; i < 4; ++i) {
        int idx = idx0 + i;
        if (idx < N_NODES) s += cnt[idx];
    }
    #pragma unroll
    for (int m = 1; m < 64; m <<= 1) s += __shfl_xor(s, m, 64);
    __shared__ int w4[4];
    if (lane == 0) w4[wid] = s;
    __syncthreads();
    if (tid == 0) csum[b] = w4[0] + w4[1] + w4[2] + w4[3];
}

// ---------------------------------------------------------------------------
// K3: scan_chunks with inlined 49-element top-scan
// ---------------------------------------------------------------------------
__global__ __launch_bounds__(256) void k3_scan_chunks_kernel(int* __restrict__ cnt,
                                                             const int* __restrict__ csum,
                                                             int* __restrict__ rp) {
    __shared__ int stop[64];
    __shared__ int wsum[4];
    const int b = blockIdx.x, tid = threadIdx.x;
    const int lane = tid & 63, wid = tid >> 6;
    if (tid < 64) stop[tid] = (tid < NC) ? csum[tid] : 0;
    __syncthreads();
    int base = 0;
    for (int w = 0; w < b; ++w) base += stop[w];
    int v[4];
    const int idx0 = b * 1024 + tid * 4;
    #pragma unroll
    for (int i = 0; i < 4; ++i) {
        int idx = idx0 + i;
        v[i] = (idx < N_NODES) ? cnt[idx] : 0;
    }
    int tsum = v[0] + v[1] + v[2] + v[3];
    int x = tsum;
    #pragma unroll
    for (int d = 1; d < 64; d <<= 1) {
        int y = __shfl_up(x, d, 64);
        if (lane >= d) x += y;
    }
    if (lane == 63) wsum[wid] = x;
    __syncthreads();
    int woff = 0;
    for (int w = 0; w < wid; ++w) woff += wsum[w];
    int excl = base + woff + x - tsum;
    #pragma unroll
    for (int i = 0; i < 4; ++i) {
        int idx = idx0 + i;
        if (idx < N_NODES) { rp[idx] = excl; cnt[idx] = excl; }
        excl += v[i];
    }
}

// ---------------------------------------------------------------------------
// K4 (fused, independent halves run concurrently):
//   [0, NB_GEMM)           : GEMM1 (MFMA) u16 = x16 @ M16t^T (128x128 tile)
//   [NB_GEMM, +NB_SCAT)    : scatter edges -> payload {src, w} (CSR by tgt)
// ---------------------------------------------------------------------------
__global__ __launch_bounds__(256) void k4_gemmu_scatter_kernel(const __half* __restrict__ x16,
                                                               const __half* __restrict__ M16t,
                                                               __half* __restrict__ u16,
                                                               const int* __restrict__ ei,
                                                               const float* __restrict__ ew,
                                                               int* __restrict__ cnt,
                                                               int2* __restrict__ payload) {
    __shared__ __half Ax[128][136];
    __shared__ __half Bm[128][136];
    const int tid = threadIdx.x;
    if (blockIdx.x >= NB_GEMM) {
        // ---- scatter ----
        int e = (blockIdx.x - NB_GEMM) * 256 + tid;
        if (e < N_EDGES) {
            int s = ei[e], t = ei[N_EDGES + e];
            int pos = atomicAdd(&cnt[t], 1);
            payload[pos] = make_int2(s, __float_as_int(ew[e]));
        }
        return;
    }
    // ---- GEMM1 ----
    const int m0 = (blockIdx.x % 391) * 128;
    const int colbase = (blockIdx.x / 391) * 128;
    {
        const int r = tid >> 1, part = tid & 1;   // 64 halves = 8 uint4/thread
        uint4 va[8];
        if (m0 + r < N_NODES) {
            const uint4* src = (const uint4*)(x16 + (size_t)(m0 + r) * IN_CH + part * 64);
            #pragma unroll
            for (int q = 0; q < 8; ++q) va[q] = src[q];
        } else {
            #pragma unroll
            for (int q = 0; q < 8; ++q) va[q] = make_uint4(0u, 0u, 0u, 0u);
        }
        uint4* da = (uint4*)&Ax[r][part * 64];
        #pragma unroll
        for (int q = 0; q < 8; ++q) da[q] = va[q];
        const uint4* sb = (const uint4*)(M16t + (size_t)(colbase + r) * IN_CH + part * 64);
        uint4* db = (uint4*)&Bm[r][part * 64];
        #pragma unroll
        for (int q = 0; q < 8; ++q) db[q] = sb[q];
    }
    __syncthreads();

    const int w = tid >> 6, lane = tid & 63;
    const int mrow = lane & 15, quad = lane >> 4;

    half8 a[2][4];
    #pragma unroll
    for (int mt = 0; mt < 2; ++mt)
        #pragma unroll
        for (int ks = 0; ks < 4; ++ks)
            a[mt][ks] = *(const half8*)&Ax[w * 32 + mt * 16 + mrow][ks * 32 + quad * 8];

    floatx4 acc[2][8];
    #pragma unroll
    for (int mt = 0; mt < 2; ++mt)
        #pragma unroll
        for (int nt = 0; nt < 8; ++nt)
            acc[mt][nt] = (floatx4){0.f, 0.f, 0.f, 0.f};

    #pragma unroll
    for (int nt = 0; nt < 8; ++nt) {
        #pragma unroll
        for (int ks = 0; ks < 4; ++ks) {
            half8 bfr = *(const half8*)&Bm[nt * 16 + mrow][ks * 32 + quad * 8];
            acc[0][nt] = __builtin_amdgcn_mfma_f32_16x16x32_f16(a[0][ks], bfr, acc[0][nt], 0, 0, 0);
            acc[1][nt] = __builtin_amdgcn_mfma_f32_16x16x32_f16(a[1][ks], bfr, acc[1][nt], 0, 0, 0);
        }
    }
    __syncthreads();
    #pragma unroll
    for (int mt = 0; mt < 2; ++mt)
        #pragma unroll
        for (int nt = 0; nt < 8; ++nt)
            #pragma unroll
            for (int r = 0; r < 4; ++r)
                Ax[w * 32 + mt * 16 + quad * 4 + r][nt * 16 + mrow] = __float2half(acc[mt][nt][r]);
    __syncthreads();
    {
        const int r = tid >> 1, part = tid & 1;
        if (m0 + r < N_NODES) {
            const uint4* s4 = (const uint4*)&Ax[r][part * 64];
            uint4* d4 = (uint4*)(u16 + (size_t)(m0 + r) * UDIM + colbase + part * 64);
            #pragma unroll
            for (int q = 0; q < 8; ++q) d4[q] = s4[q];
        }
    }
}

// ---------------------------------------------------------------------------
// Fused edge kernel v5 (round-15 best): LDS payload staging + head-striped
// lanes. Block = 16 consecutive tgt nodes -> ONE contiguous payload span.
// ---------------------------------------------------------------------------
__global__ __launch_bounds__(256) void edge_fused_kernel(const __half* __restrict__ u16,
                                                         const __half* __restrict__ x16,
                                                         const int* __restrict__ rp,
                                                         const int* __restrict__ cnt,
                                                         const int2* __restrict__ payload,
                                                         const float* __restrict__ We,
                                                         __half* __restrict__ y16,
                                                         double* __restrict__ S) {
    __shared__ int2 pbuf[PCAP];
    __shared__ float sblk[4];
    const int tid = threadIdx.x;
    const int nodebase = blockIdx.x * 16;

    const int span0 = rp[nodebase];
    const int span1 = cnt[nodebase + 15];
    const int span_len = min(span1 - span0, PCAP);
    for (int i = tid; i < span_len; i += 256) pbuf[i] = payload[span0 + i];
    if (tid < 4) sblk[tid] = 0.f;
    __syncthreads();

    const int l16 = tid & 15;
    const int h = l16 >> 2;          // head 0..3
    const int q = l16 & 3;           // channel quarter 0..3
    const int node = nodebase + (tid >> 4);
    const float wev = We[h];

    uint4 ur4[4];
    {
        const uint4* ub = (const uint4*)(u16 + (size_t)node * UDIM + h * 128 + q * 32);
        ur4[0] = ub[0]; ur4[1] = ub[1]; ur4[2] = ub[2]; ur4[3] = ub[3];
    }
    const half2_t* uh = (const half2_t*)ur4;    // 16 half2

    half2_t yacc[16];
    #pragma unroll
    for (int t = 0; t < 16; ++t) yacc[t] = (half2_t){(_Float16)0.f, (_Float16)0.f};

    float sacc = 0.f;
    const int start = rp[node];
    const int end = cnt[node];

    auto getpl = [&](int e) -> int2 {
        int idx = e - span0;
        return (idx < PCAP) ? pbuf[idx] : payload[e];
    };

    int2 pl = make_int2(0, 0);
    uint4 xr[4];
    if (start < end) {
        pl = getpl(start);
        const uint4* xb = (const uint4*)(x16 + (size_t)pl.x * IN_CH + q * 32);
        xr[0] = xb[0]; xr[1] = xb[1]; xr[2] = xb[2]; xr[3] = xb[3];
    }
    for (int e = start; e < end; ++e) {
        int2 pln = pl;
        uint4 xrn[4] = {xr[0], xr[1], xr[2], xr[3]};
        if (e + 1 < end) {
            pln = getpl(e + 1);
            const uint4* xb = (const uint4*)(x16 + (size_t)pln.x * IN_CH + q * 32);
            xrn[0] = xb[0]; xrn[1] = xb[1]; xrn[2] = xb[2]; xrn[3] = xb[3];
        }
        const half2_t* xh = (const half2_t*)xr;
        float dot = 0.f;
        #pragma unroll
        for (int t = 0; t < 16; ++t)
            dot = __builtin_amdgcn_fdot2(uh[t], xh[t], dot, false);
        dot += __shfl_xor(dot, 1, 16);
        dot += __shfl_xor(dot, 2, 16);
        float l = dot * 0.125f + __int_as_float(pl.y) * wev;
        l = fmaxf(l, 0.2f * l);          // leaky_relu(0.2)
        float p = __expf(l);
        if (q == 0) sacc += p;
        half2_t p2 = (half2_t){(_Float16)p, (_Float16)p};
        #pragma unroll
        for (int t = 0; t < 16; ++t)
            yacc[t] = p2 * xh[t] + yacc[t];   // v_pk_fma_f16
        pl = pln;
        xr[0] = xrn[0]; xr[1] = xrn[1]; xr[2] = xrn[2]; xr[3] = xrn[3];
    }
    {
        uint4* yo = (uint4*)(y16 + (size_t)node * UDIM + h * 128 + q * 32);
        const uint4* ys = (const uint4*)yacc;
        yo[0] = ys[0]; yo[1] = ys[1]; yo[2] = ys[2]; yo[3] = ys[3];
    }
    __syncthreads();
    if (q == 0) atomicAdd(&sblk[h], sacc);
    __syncthreads();
    if (tid < 4) atomicAdd(&S[tid], (double)sblk[tid]);
}

// ---------------------------------------------------------------------------
// GEMM2 (MFMA): out[50000x64] = sum_h invs[h] * (y16_h @ Zc16t_h^T) + b_out.
// ---------------------------------------------------------------------------
__global__ __launch_bounds__(256) void gemm_out_mfma_kernel(const __half* __restrict__ y16,
                                                            const __half* __restrict__ Zc16t,
                                                            const double* __restrict__ S,
                                                            const float* __restrict__ b_out,
                                                            float* __restrict__ out) {
    __shared__ __half Ay[128][136];
    __shared__ __half Bz[64][136];
    __shared__ float invs_s[4];
    const int m0 = blockIdx.x * 128;
    const int tid = threadIdx.x;
    if (tid < 4) invs_s[tid] = (float)(1.0 / S[tid]);

    const int w = tid >> 6, lane = tid & 63;
    const int mrow = lane & 15, quad = lane >> 4;

    floatx4 result[2][4];
    #pragma unroll
    for (int mt = 0; mt < 2; ++mt)
        #pragma unroll
        for (int nt = 0; nt < 4; ++nt)
            result[mt][nt] = (floatx4){0.f, 0.f, 0.f, 0.f};

    for (int h = 0; h < HEADS; ++h) {
        {
            const int r = tid >> 1, part = tid & 1;   // 8 uint4/thread
            uint4 va[8];
            if (m0 + r < N_NODES) {
                const uint4* src = (const uint4*)(y16 + (size_t)(m0 + r) * UDIM + h * 128 + part * 64);
                #pragma unroll
                for (int qq = 0; qq < 8; ++qq) va[qq] = src[qq];
            } else {
                #pragma unroll
                for (int qq = 0; qq < 8; ++qq) va[qq] = make_uint4(0u, 0u, 0u, 0u);
            }
            uint4* da = (uint4*)&Ay[r][part * 64];
            #pragma unroll
            for (int qq = 0; qq < 8; ++qq) da[qq] = va[qq];
        }
        {
            const int r = tid >> 2, part = tid & 3;   // 4 uint4/thread
            const uint4* sb = (const uint4*)(Zc16t + (size_t)r * UDIM + h * 128 + part * 32);
            uint4* db = (uint4*)&Bz[r][part * 32];
            #pragma unroll
            for (int qq = 0; qq < 4; ++qq) db[qq] = sb[qq];
        }
        __syncthreads();

        half8 a[2][4];
        #pragma unroll
        for (int mt = 0; mt < 2; ++mt)
            #pragma unroll
            for (int ks = 0; ks < 4; ++ks)
                a[mt][ks] = *(const half8*)&Ay[w * 32 + mt * 16 + mrow][ks * 32 + quad * 8];

        floatx4 acc[2][4];
        #pragma unroll
        for (int mt = 0; mt < 2; ++mt)
            #pragma unroll
            for (int nt = 0; nt < 4; ++nt)
                acc[mt][nt] = (floatx4){0.f, 0.f, 0.f, 0.f};

        #pragma unroll
        for (int nt = 0; nt < 4; ++nt) {
            #pragma unroll
            for (int ks = 0; ks < 4; ++ks) {
                half8 bfr = *(const half8*)&Bz[nt * 16 + mrow][ks * 32 + quad * 8];
                acc[0][nt] = __builtin_amdgcn_mfma_f32_16x16x32_f16(a[0][ks], bfr, acc[0][nt], 0, 0, 0);
                acc[1][nt] = __builtin_amdgcn_mfma_f32_16x16x32_f16(a[1][ks], bfr, acc[1][nt], 0, 0, 0);
            }
        }
        const float inv = invs_s[h];
        #pragma unroll
        for (int mt = 0; mt < 2; ++mt)
            #pragma unroll
            for (int nt = 0; nt < 4; ++nt) {
                result[mt][nt][0] += inv * acc[mt][nt][0];
                result[mt][nt][1] += inv * acc[mt][nt][1];
                result[mt][nt][2] += inv * acc[mt][nt][2];
                result[mt][nt][3] += inv * acc[mt][nt][3];
            }
        __syncthreads();
    }
    float bcol[4];
    #pragma unroll
    for (int nt = 0; nt < 4; ++nt) bcol[nt] = b_out[nt * 16 + mrow];
    #pragma unroll
    for (int mt = 0; mt < 2; ++mt) {
        #pragma unroll
        for (int r = 0; r < 4; ++r) {
            int row = m0 + w * 32 + mt * 16 + quad * 4 + r;
            if (row < N_NODES) {
                float* dst = out + (size_t)row * OUT_CH;
                #pragma unroll
                for (int nt = 0; nt < 4; ++nt)
                    dst[nt * 16 + mrow] = result[mt][nt][r] + bcol[nt];
            }
        }
    }
}

// ---------------------------------------------------------------------------
// Launch
// ---------------------------------------------------------------------------
extern "C" void kernel_launch(void* const* d_in, const int* in_sizes, int n_in,
                              void* d_out, int out_size, void* d_ws, size_t ws_size,
                              hipStream_t stream) {
    const float* x     = (const float*)d_in[0];
    const int*   ei    = (const int*)d_in[1];   // [2, E] int32
    const float* ew    = (const float*)d_in[2];
    const float* Wq    = (const float*)d_in[3];
    const float* Wk    = (const float*)d_in[4];
    const float* Wv    = (const float*)d_in[5];
    const float* We    = (const float*)d_in[6];
    const float* Wout  = (const float*)d_in[7];
    const float* b_out = (const float*)d_in[8];
    float* out = (float*)d_out;

    // workspace layout (~120 MB)
    __half* u16   = (__half*)d_ws;                          // 50000*512*2 = 51.2 MB
    __half* y16   = u16 + (size_t)N_NODES * UDIM;           // 51.2 MB
    __half* x16   = y16 + (size_t)N_NODES * UDIM;           // 12.8 MB
    double* S     = (double*)(x16 + (size_t)N_NODES * IN_CH);  // 4 doubles
    __half* M16t  = (__half*)(S + HEADS);                   // 512*128*2 = 128 KB
    __half* Zc16t = M16t + UDIM * IN_CH;                    // 64*512*2 = 64 KB
    int*    rp    = (int*)(Zc16t + OUT_CH * UDIM);          // 50000
    int*    cnt   = rp + N_NODES;                           // 50000
    int*    csum  = cnt + N_NODES;                          // 64
    int2*   payload = (int2*)(csum + 64);                   // 500000*8 = 4 MB

    hipMemsetAsync(cnt, 0, N_NODES * sizeof(int), stream);
    k1_prep_kernel<<<NB_X16 + NB_HIST + NB_MB + NB_ZB, 256, 0, stream>>>(
        x, x16, ei, cnt, S, Wq, Wk, Wv, Wout, M16t, Zc16t);
    k2_scan_reduce_kernel<<<NC, 256, 0, stream>>>(cnt, csum);
    k3_scan_chunks_kernel<<<NC, 256, 0, stream>>>(cnt, csum, rp);
    k4_gemmu_scatter_kernel<<<NB_GEMM + NB_SCAT, 256, 0, stream>>>(
        x16, M16t, u16, ei, ew, cnt, payload);
    edge_fused_kernel<<<N_NODES / 16, 256, 0, stream>>>(u16, x16, rp, cnt, payload, We, y16, S);
    gemm_out_mfma_kernel<<<(N_NODES + 127) / 128, 256, 0, stream>>>(y16, Zc16t, S, b_out, out);
}